// Round 7
// baseline (20.718 us; speedup 1.0000x reference)
//
#include <hip/hip_runtime.h>

// MorphTEmbedding R7: minimal-instruction formulation. One wave per token.
// Layout e = lane*8 + j  =>  a = lane>>3, b = lane&7, c = j.
//  - A,B: 16 dword broadcast loads (32B footprint each)
//  - C rows: 16 broadcast float4 loads (2 per rank) -> VGPRs, no readlanes
//  - LN params: 4 float4 loads; stores: 2 nontemporal dwordx4 (16B/lane)
//  - LN reduce: DPP butterfly + 2 shfl_xor, zero DS ops
// var = E[v^2]-mu^2 (var ~1e-12 << eps=1e-5; validated R2-R6).

#define RANK      8
#define NUM_MORPH 10000
#define EMB       512
#define LN_EPS    1e-5f
#define WPB       4                 // waves per block (256 threads)
#define RSTRIDE   80000             // floats between ranks in W

typedef float f32x4 __attribute__((ext_vector_type(4)));

template <int CTRL>
__device__ __forceinline__ float dpp_add(float v) {
    return v + __int_as_float(__builtin_amdgcn_update_dpp(
        __float_as_int(v), __float_as_int(v), CTRL, 0xf, 0xf, false));
}
__device__ __forceinline__ float rdlane(float v, int l) {
    return __int_as_float(__builtin_amdgcn_readlane(__float_as_int(v), l));
}

__global__ __launch_bounds__(256) void morph_emb_kernel(
    const int* __restrict__ x,       // [n_tok]
    const int* __restrict__ co,      // [NUM_SURF, 3]
    const float* __restrict__ W,     // [RANK, NUM_MORPH, 8]
    const float* __restrict__ lns,   // [512]
    const float* __restrict__ lnb,   // [512]
    float* __restrict__ out,         // [n_tok, 512]
    int n_tok) {
    const int lane = threadIdx.x & 63;
    const int wid  = blockIdx.x * WPB + (threadIdx.x >> 6);
    const int tok  = (wid < n_tok) ? wid : (n_tok - 1);

    // token chain (wave-uniform values, plain loads)
    const int s  = x[tok];
    const int m0 = co[s * 3 + 0];
    const int m1 = co[s * 3 + 1];
    const int m2 = co[s * 3 + 2];

    const float* pa = W + (size_t)m0 * 8 + (lane >> 3);
    const float* pb = W + (size_t)m1 * 8 + (lane & 7);
    const float* pc = W + (size_t)m2 * 8;

    // per-rank per-lane product p = A*B, and C rows as float4 pairs
    float p[RANK];
    f32x4 c0[RANK], c1[RANK];
#pragma unroll
    for (int r = 0; r < RANK; ++r) {
        p[r]  = pa[r * RSTRIDE] * pb[r * RSTRIDE];
        c0[r] = *reinterpret_cast<const f32x4*>(pc + r * RSTRIDE);
        c1[r] = *reinterpret_cast<const f32x4*>(pc + r * RSTRIDE + 4);
    }

    float acc[8] = {0.f, 0.f, 0.f, 0.f, 0.f, 0.f, 0.f, 0.f};
#pragma unroll
    for (int r = 0; r < RANK; ++r) {
        acc[0] = fmaf(p[r], c0[r][0], acc[0]);
        acc[1] = fmaf(p[r], c0[r][1], acc[1]);
        acc[2] = fmaf(p[r], c0[r][2], acc[2]);
        acc[3] = fmaf(p[r], c0[r][3], acc[3]);
        acc[4] = fmaf(p[r], c1[r][0], acc[4]);
        acc[5] = fmaf(p[r], c1[r][1], acc[5]);
        acc[6] = fmaf(p[r], c1[r][2], acc[6]);
        acc[7] = fmaf(p[r], c1[r][3], acc[7]);
    }

    // ---- LayerNorm stats: DPP row-16 reduce + cross-row shfl (zero DS) ----
    float sm = 0.f, sq = 0.f;
#pragma unroll
    for (int j = 0; j < 8; ++j) { sm += acc[j]; sq += acc[j] * acc[j]; }
    sm = dpp_add<0xB1>(sm);  sq = dpp_add<0xB1>(sq);   // quad xor1
    sm = dpp_add<0x4E>(sm);  sq = dpp_add<0x4E>(sq);   // quad xor2
    sm = dpp_add<0x141>(sm); sq = dpp_add<0x141>(sq);  // row_half_mirror
    sm = dpp_add<0x140>(sm); sq = dpp_add<0x140>(sq);  // row_mirror
    const float tot_s = (rdlane(sm, 0) + rdlane(sm, 16)) +
                        (rdlane(sm, 32) + rdlane(sm, 48));
    const float tot_q = (rdlane(sq, 0) + rdlane(sq, 16)) +
                        (rdlane(sq, 32) + rdlane(sq, 48));
    const float mu = tot_s * (1.0f / EMB);
    const float rs = rsqrtf(tot_q * (1.0f / EMB) - mu * mu + LN_EPS);

    // ---- normalize + store (2x nontemporal dwordx4 per lane) ----
    const int e = lane << 3;
    const f32x4 g0 = *reinterpret_cast<const f32x4*>(lns + e);
    const f32x4 g1 = *reinterpret_cast<const f32x4*>(lns + e + 4);
    const f32x4 b0 = *reinterpret_cast<const f32x4*>(lnb + e);
    const f32x4 b1 = *reinterpret_cast<const f32x4*>(lnb + e + 4);

    if (wid < n_tok) {
        f32x4 o0, o1;
        o0[0] = (acc[0] - mu) * rs * g0[0] + b0[0];
        o0[1] = (acc[1] - mu) * rs * g0[1] + b0[1];
        o0[2] = (acc[2] - mu) * rs * g0[2] + b0[2];
        o0[3] = (acc[3] - mu) * rs * g0[3] + b0[3];
        o1[0] = (acc[4] - mu) * rs * g1[0] + b1[0];
        o1[1] = (acc[5] - mu) * rs * g1[1] + b1[1];
        o1[2] = (acc[6] - mu) * rs * g1[2] + b1[2];
        o1[3] = (acc[7] - mu) * rs * g1[3] + b1[3];
        f32x4* op = reinterpret_cast<f32x4*>(out + (size_t)wid * EMB + e);
        __builtin_nontemporal_store(o0, op);
        __builtin_nontemporal_store(o1, op + 1);
    }
}

extern "C" void kernel_launch(void* const* d_in, const int* in_sizes, int n_in,
                              void* d_out, int out_size, void* d_ws, size_t ws_size,
                              hipStream_t stream) {
    const int*   x   = (const int*)d_in[0];
    const int*   co  = (const int*)d_in[1];
    const float* W   = (const float*)d_in[2];
    const float* lns = (const float*)d_in[3];
    const float* lnb = (const float*)d_in[4];
    float*       out = (float*)d_out;

    const int n_tok  = in_sizes[0];                 // 16384
    const int blocks = (n_tok + WPB - 1) / WPB;     // 4096
    morph_emb_kernel<<<blocks, WPB * 64, 0, stream>>>(x, co, W, lns, lnb, out, n_tok);
}

// Round 8
// 18.155 us; speedup vs baseline: 1.1412x; 1.1412x over previous
//
#include <hip/hip_runtime.h>

// MorphTEmbedding R8: R6 (zero-DS, one wave/token, 16.5us) + L2 warm phase.
// Theory: floor is random-64B HBM fetch of W/co (L2 evicted between replays
// by the harness's 262MB poison fills). Warm phase streams W+co coalesced
// into each XCD's L2 before the data-dependent random gathers arrive.

#define RANK      8
#define NUM_MORPH 10000
#define EMB       512
#define LN_EPS    1e-5f
#define WPB       4                 // waves per block (256 threads)
#define RSTRIDE   80000             // floats between ranks in W

typedef float f32x4 __attribute__((ext_vector_type(4)));

template <int CTRL>
__device__ __forceinline__ float dpp_add(float v) {
    return v + __int_as_float(__builtin_amdgcn_update_dpp(
        __float_as_int(v), __float_as_int(v), CTRL, 0xf, 0xf, false));
}
__device__ __forceinline__ float rdlane(float v, int l) {
    return __int_as_float(__builtin_amdgcn_readlane(__float_as_int(v), l));
}

__global__ __launch_bounds__(256) void morph_emb_kernel(
    const int* __restrict__ x,       // [n_tok]
    const int* __restrict__ co,      // [NUM_SURF, 3]
    const float* __restrict__ W,     // [RANK, NUM_MORPH, 8] = 640000 floats
    const float* __restrict__ lns,   // [512]
    const float* __restrict__ lnb,   // [512]
    float* __restrict__ out,         // [n_tok, 512]
    int n_tok) {
    const int lane = threadIdx.x & 63;
    const int wid  = blockIdx.x * WPB + (threadIdx.x >> 6);
    const int tok  = (wid < n_tok) ? wid : (n_tok - 1);   // clamp, no divergence

    // ---- L2 warm phase (issued first, before any dependent chain) ----
    // Blocks with equal (blockIdx&7) land on the same XCD (round-robin
    // heuristic); together they stream ALL of W (160000 float4) and co
    // (37500 int4) so the XCD's L2 holds the tables before the random
    // gathers (delayed behind x->co) arrive. Coalesced dwordx4, <=3/thread.
    {
        const int rb = (int)(blockIdx.x >> 3);          // 0..511 within XCD
        const int t  = (int)threadIdx.x;                // 0..255
        const f32x4* Wv = reinterpret_cast<const f32x4*>(W);
        float keep = 0.f;
        const int i0 = rb * 320 + t;
        if (i0 < 160000) { f32x4 v = Wv[i0]; keep += (v[0] + v[1]) + (v[2] + v[3]); }
        const int i1 = rb * 320 + 256 + t;
        if (t < 64 && i1 < 160000) { f32x4 v = Wv[i1]; keep += (v[0] + v[1]) + (v[2] + v[3]); }
        const int4* cv = reinterpret_cast<const int4*>(co);
        const int i2 = rb * 80 + t;
        if (t < 80 && i2 < 37500) { int4 v = cv[i2]; keep += (float)(v.x ^ v.y ^ v.z ^ v.w); }
        asm volatile("" :: "v"(keep));   // keep loads alive (no DCE)
    }

    // LN params (token-invariant): g[j]=lns[j*64+lane]
    float gv[8], bv[8];
#pragma unroll
    for (int j = 0; j < 8; ++j) {
        gv[j] = lns[j * 64 + lane];
        bv[j] = lnb[j * 64 + lane];
    }

    // token chain (wave-uniform values, plain loads)
    const int s  = x[tok];
    const int m0 = co[s * 3 + 0];
    const int m1 = co[s * 3 + 1];
    const int m2 = co[s * 3 + 2];

    // A distribution: lane (r=lane>>3, d=lane&7) holds W[r, m0, d] — ONE load
    const float a_mine =
        W[(size_t)(lane >> 3) * RSTRIDE + (size_t)m0 * 8 + (lane & 7)];

    // B,C per-lane scalars (broadcast loads, 32B footprint each)
    const float* pb = W + (size_t)m1 * 8 + (lane >> 3);
    const float* pc = W + (size_t)m2 * 8 + (lane & 7);
    float p[RANK];
#pragma unroll
    for (int r = 0; r < RANK; ++r)
        p[r] = pb[r * RSTRIDE] * pc[r * RSTRIDE];

    // acc[j] = sum_r p[r] * A[r][j]; A via readlane -> SGPR operand of v_fmac
    float acc[8] = {0.f, 0.f, 0.f, 0.f, 0.f, 0.f, 0.f, 0.f};
#pragma unroll
    for (int r = 0; r < RANK; ++r) {
#pragma unroll
        for (int j = 0; j < 8; ++j)
            acc[j] = fmaf(p[r], rdlane(a_mine, r * 8 + j), acc[j]);
    }

    // ---- LayerNorm stats: DPP row-16 reduce + 4 readlanes (zero DS) ----
    float sm = 0.f, sq = 0.f;
#pragma unroll
    for (int j = 0; j < 8; ++j) { sm += acc[j]; sq += acc[j] * acc[j]; }
    sm = dpp_add<0xB1>(sm);  sq = dpp_add<0xB1>(sq);
    sm = dpp_add<0x4E>(sm);  sq = dpp_add<0x4E>(sq);
    sm = dpp_add<0x141>(sm); sq = dpp_add<0x141>(sq);
    sm = dpp_add<0x140>(sm); sq = dpp_add<0x140>(sq);
    const float tot_s = (rdlane(sm, 0) + rdlane(sm, 16)) +
                        (rdlane(sm, 32) + rdlane(sm, 48));
    const float tot_q = (rdlane(sq, 0) + rdlane(sq, 16)) +
                        (rdlane(sq, 32) + rdlane(sq, 48));
    const float mu = tot_s * (1.0f / EMB);
    const float rs = rsqrtf(tot_q * (1.0f / EMB) - mu * mu + LN_EPS);

    // ---- normalize + store: 8 fully-coalesced 256B dword stores ----
    if (wid < n_tok) {
        float* op = out + (size_t)wid * EMB + lane;
#pragma unroll
        for (int j = 0; j < 8; ++j)
            op[j * 64] = (acc[j] - mu) * rs * gv[j] + bv[j];
    }
}

extern "C" void kernel_launch(void* const* d_in, const int* in_sizes, int n_in,
                              void* d_out, int out_size, void* d_ws, size_t ws_size,
                              hipStream_t stream) {
    const int*   x   = (const int*)d_in[0];
    const int*   co  = (const int*)d_in[1];
    const float* W   = (const float*)d_in[2];
    const float* lns = (const float*)d_in[3];
    const float* lnb = (const float*)d_in[4];
    float*       out = (float*)d_out;

    const int n_tok  = in_sizes[0];                 // 16384
    const int blocks = (n_tok + WPB - 1) / WPB;     // 4096
    morph_emb_kernel<<<blocks, WPB * 64, 0, stream>>>(x, co, W, lns, lnb, out, n_tok);
}